// Round 2
// baseline (120.184 us; speedup 1.0000x reference)
//
#include <hip/hip_runtime.h>
#include <math.h>

#define BB 4
#define LL 1024
#define DD 1024
#define KK 20
#define CC 21
#define LC (LL * CC)          // 21504 floats per (b, i) output row-panel

__device__ __forceinline__ float wave_reduce_sum(float v) {
    #pragma unroll
    for (int off = 1; off < 64; off <<= 1)
        v += __shfl_xor(v, off, 64);
    return v;
}

// ---------------------------------------------------------------------------
// Kernel 0: zd[k,c] = dic[k,:] . Wz_w[c,:] + Wz_b[c]       (e in [0,420))
//           M [k,c] = dic[k,:] . cs_w[c, D:2D]             (e in [420,840))
// one wave per entry
// ---------------------------------------------------------------------------
__global__ __launch_bounds__(64) void k0_zdM(
    const float* __restrict__ dic,
    const float* __restrict__ Wz_w, const float* __restrict__ Wz_b,
    const float* __restrict__ cs_w,
    float* __restrict__ zd, float* __restrict__ M)
{
    int e = blockIdx.x;                 // 0..2*K*C-1
    int lane = threadIdx.x;
    bool isM = (e >= KK * CC);
    int e2 = isM ? e - KK * CC : e;
    int k = e2 / CC, c = e2 % CC;
    const float* a = dic + k * DD;
    const float* w = isM ? (cs_w + (size_t)c * (2 * DD) + DD) : (Wz_w + c * DD);
    float p = 0.f;
    #pragma unroll
    for (int i = 0; i < DD / 64; ++i) {
        int d = lane + 64 * i;
        p += a[d] * w[d];
    }
    p = wave_reduce_sum(p);
    if (lane == 0) {
        if (isM) M[e2] = p;
        else     zd[e2] = p + Wz_b[c];
    }
}

// ---------------------------------------------------------------------------
// Kernel 1: one wave handles 4 consecutive rows (amortizes the 172 KB weight
// panel 4x). After each dual reduction, lane keeps the result for row lane&3.
// Softmax + lz computed redundantly per lane (cheap); lanes 0..3 store.
// ---------------------------------------------------------------------------
__global__ __launch_bounds__(64) void k1_rows(
    const float* __restrict__ x,
    const float* __restrict__ prior,
    const float* __restrict__ Wy_w, const float* __restrict__ Wy_b,
    const float* __restrict__ cs_w, const float* __restrict__ cs_b,
    const float* __restrict__ zd, const float* __restrict__ M,
    float* __restrict__ ly_ws, float* __restrict__ lz_ws)
{
    int lane = threadIdx.x;
    int r0 = blockIdx.x * 4;            // 1024 blocks * 4 rows = 4096

    __shared__ float zds[KK * CC];
    __shared__ float Ms[KK * CC];
    for (int i = lane; i < KK * CC; i += 64) {
        zds[i] = zd[i];
        Ms[i]  = M[i];
    }

    float yv[4][DD / 64];
    #pragma unroll
    for (int r = 0; r < 4; ++r) {
        const float* y = x + (size_t)(r0 + r) * DD;
        #pragma unroll
        for (int i = 0; i < DD / 64; ++i) yv[r][i] = y[lane + 64 * i];
    }
    __syncthreads();

    int myrow = lane & 3;
    float myw[CC], myly[CC];

    #pragma unroll
    for (int c = 0; c < CC; ++c) {
        const float* w1 = Wy_w + c * DD;
        const float* w2 = cs_w + (size_t)c * (2 * DD);     // first half
        float p1[4] = {0.f, 0.f, 0.f, 0.f};
        float p2[4] = {0.f, 0.f, 0.f, 0.f};
        #pragma unroll
        for (int i = 0; i < DD / 64; ++i) {
            int d = lane + 64 * i;
            float wa = w1[d];
            float wb = w2[d];
            #pragma unroll
            for (int r = 0; r < 4; ++r) {
                p1[r] += yv[r][i] * wa;
                p2[r] += yv[r][i] * wb;
            }
        }
        #pragma unroll
        for (int r = 0; r < 4; ++r) {
            p1[r] = wave_reduce_sum(p1[r]);
            p2[r] = wave_reduce_sum(p2[r]);
        }
        float s1 = p1[0], s2 = p2[0];
        if (myrow == 1) { s1 = p1[1]; s2 = p2[1]; }
        if (myrow == 2) { s1 = p1[2]; s2 = p2[2]; }
        if (myrow == 3) { s1 = p1[3]; s2 = p2[3]; }
        myw[c]  = s1 + Wy_b[c];
        myly[c] = s2;
    }

    // softmax over K for this lane's row (redundant across the 16 owner lanes)
    const float scale = 0.2182178902359924f;   // 1/sqrt(21)
    float s[KK];
    float m = -1e30f;
    #pragma unroll
    for (int k = 0; k < KK; ++k) {
        float t = 0.f;
        #pragma unroll
        for (int c = 0; c < CC; ++c) t += myw[c] * zds[k * CC + c];
        s[k] = t * scale;
        m = fmaxf(m, s[k]);
    }
    float sum = 0.f;
    #pragma unroll
    for (int k = 0; k < KK; ++k) { s[k] = expf(s[k] - m); sum += s[k]; }
    float inv = 1.f / sum;
    float wk[KK];
    #pragma unroll
    for (int k = 0; k < KK; ++k) wk[k] = s[k] * inv * prior[k];

    float mlz[CC];
    #pragma unroll
    for (int c = 0; c < CC; ++c) {
        float t = cs_b[c];
        #pragma unroll
        for (int k = 0; k < KK; ++k) t += wk[k] * Ms[k * CC + c];
        mlz[c] = t;
    }

    if (lane < 4) {
        float* lyp = ly_ws + (size_t)(r0 + lane) * CC;
        float* lzp = lz_ws + (size_t)(r0 + lane) * CC;
        #pragma unroll
        for (int c = 0; c < CC; ++c) { lyp[c] = myly[c]; lzp[c] = mlz[c]; }
    }
}

// ---------------------------------------------------------------------------
// Kernel 2: outer-sum write, 8 i's per block. Thread caches its slice of
// lz[b] (11 float4) in registers; ly[8][21] in LDS. Pure coalesced writes.
// ---------------------------------------------------------------------------
__global__ __launch_bounds__(512) void k2_outer(
    const float* __restrict__ ly_ws, const float* __restrict__ lz_ws,
    float* __restrict__ out)
{
    int tid = threadIdx.x;
    int blk = blockIdx.x;               // 0..511
    int b  = blk >> 7;                  // / 128
    int i0 = (blk & 127) << 3;          // * 8

    __shared__ float lys[8 * CC];
    if (tid < 8 * CC) lys[tid] = ly_ws[(size_t)(b * LL + i0) * CC + tid];

    const float* lzp = lz_ws + (size_t)b * LC;
    float4 lzv[11];
    int c0s[11];
    #pragma unroll
    for (int it = 0; it < 11; ++it) {
        int idx = tid + it * 512;
        if (idx < LC / 4) {
            lzv[it] = *reinterpret_cast<const float4*>(lzp + idx * 4);
        } else {
            lzv[it] = make_float4(0.f, 0.f, 0.f, 0.f);
        }
        c0s[it] = (idx * 4) % 21;
    }
    __syncthreads();

    #pragma unroll
    for (int i = 0; i < 8; ++i) {
        float* op = out + (size_t)(b * LL + i0 + i) * LC;
        const float* ly = lys + i * CC;
        #pragma unroll
        for (int it = 0; it < 11; ++it) {
            int idx = tid + it * 512;
            if (idx < LC / 4) {
                int c0 = c0s[it];
                int c1 = c0 + 1; if (c1 == 21) c1 = 0;
                int c2 = c1 + 1; if (c2 == 21) c2 = 0;
                int c3 = c2 + 1; if (c3 == 21) c3 = 0;
                float4 o;
                o.x = lzv[it].x + ly[c0];
                o.y = lzv[it].y + ly[c1];
                o.z = lzv[it].z + ly[c2];
                o.w = lzv[it].w + ly[c3];
                *reinterpret_cast<float4*>(op + idx * 4) = o;
            }
        }
    }
}

extern "C" void kernel_launch(void* const* d_in, const int* in_sizes, int n_in,
                              void* d_out, int out_size, void* d_ws, size_t ws_size,
                              hipStream_t stream)
{
    const float* x     = (const float*)d_in[0];
    const float* dic   = (const float*)d_in[1];
    const float* prior = (const float*)d_in[2];
    const float* Wy_w  = (const float*)d_in[3];
    const float* Wy_b  = (const float*)d_in[4];
    const float* Wz_w  = (const float*)d_in[5];
    const float* Wz_b  = (const float*)d_in[6];
    const float* cs_w  = (const float*)d_in[7];
    const float* cs_b  = (const float*)d_in[8];
    float* out = (float*)d_out;

    float* ws = (float*)d_ws;
    float* zd = ws;                       // 420 floats
    float* M  = ws + 512;                 // 420 floats
    float* ly = ws + 1024;                // B*L*C = 86016 floats
    float* lz = ly + BB * LL * CC;        // 86016 floats

    k0_zdM <<<dim3(2 * KK * CC), dim3(64),  0, stream>>>(dic, Wz_w, Wz_b, cs_w, zd, M);
    k1_rows<<<dim3(BB * LL / 4), dim3(64),  0, stream>>>(x, prior, Wy_w, Wy_b, cs_w, cs_b,
                                                         zd, M, ly, lz);
    k2_outer<<<dim3(BB * LL / 8 / 16 * 16), dim3(512), 0, stream>>>(ly, lz, out);
}